// Round 5
// baseline (264.091 us; speedup 1.0000x reference)
//
#include <hip/hip_runtime.h>

typedef _Float16 f16;
typedef _Float16 f16x8 __attribute__((ext_vector_type(8)));
typedef float f32x16 __attribute__((ext_vector_type(16)));
typedef unsigned int u32;
typedef unsigned int u32x4 __attribute__((ext_vector_type(4)));

#define THREADS 512
#define MTILE   128
#define NBLK    256

// LDS layout (bytes)
#define H1_OFF   0        // 2 bufs × f16[128 rows][512B], 16B XOR key (r&15)<<4
#define XS_OFF   131072   // 2 bufs × f32[128*3] = 2×1536
#define PART_OFF 134144   // 2 bufs × [4 cw][128 row][3] f32 = 2×6144
#define LDS_BYTES 146432

__global__ __launch_bounds__(THREADS, 1)
void fused_mlp_parity(const float* __restrict__ x,
                      const float* __restrict__ w1,
                      const float* __restrict__ b1,
                      const float* __restrict__ w2,
                      const float* __restrict__ b2,
                      const float* __restrict__ w3,
                      const float* __restrict__ b3,
                      float* __restrict__ out, int Bsz) {
  __shared__ __align__(128) unsigned char lds[LDS_BYTES];
  const int tid  = threadIdx.x;
  const int lane = tid & 63;
  const int wave = tid >> 6;
  const int arow = lane & 31;
  const int half = lane >> 5;
  const int cw   = wave & 3;          // col-wave: owns 64 h-cols
  const int rw   = wave >> 2;         // row-wave: owns 64 batch rows
  const int mhalf  = cw * 64;
  const int rowblk = rw * 64;

  const int ntiles = Bsz / MTILE;
  const int tpb    = ntiles / NBLK;   // 32 at B=1M
  const int t0     = blockIdx.x * tpb;

  float* xsf   = (float*)(lds + XS_OFF);    // + buf*384 floats
  float* partf = (float*)(lds + PART_OFF);  // + buf*1536 floats

  // ---- prologue: stage xs[0], xs[1] ----
  {
    const float4* xg = (const float4*)x;
    if (tid < 96)       ((float4*)xsf)[tid]       = xg[(size_t)t0*96 + tid];
    else if (tid < 192) ((float4*)xsf)[96 + tid-192+96] = xg[(size_t)(t0+1)*96 + (tid-96)];
  }

  // ---- register-resident operands ----
  f16x8 w2A[2][16];
#pragma unroll
  for (int mt = 0; mt < 2; ++mt) {
    const int col = mhalf + mt*32 + arow;
#pragma unroll
    for (int ks = 0; ks < 16; ++ks) {
      const float* src = w2 + (size_t)col*256 + ks*16 + half*8;
      float4 u0 = *(const float4*)src;
      float4 u1 = *(const float4*)(src + 4);
      f16x8 v;
      v[0]=(f16)u0.x; v[1]=(f16)u0.y; v[2]=(f16)u0.z; v[3]=(f16)u0.w;
      v[4]=(f16)u1.x; v[5]=(f16)u1.y; v[6]=(f16)u1.z; v[7]=(f16)u1.w;
      w2A[mt][ks] = v;
    }
  }
  f16x8 w1A[2];
#pragma unroll
  for (int mt = 0; mt < 2; ++mt) {
    f16x8 v = {};
    if (half == 0) {
      const int col = mhalf + mt*32 + arow;
      v[0] = (f16)w1[col*3+0]; v[1] = (f16)w1[col*3+1];
      v[2] = (f16)w1[col*3+2]; v[3] = (f16)b1[col];
    }
    w1A[mt] = v;
  }
  f16x8 b2A[2];
#pragma unroll
  for (int mt = 0; mt < 2; ++mt) {
    f16x8 v = {};
    if (half == 0) v[0] = (f16)b2[mhalf + mt*32 + arow];
    b2A[mt] = v;
  }
  f16x8 ones = {}; if (half == 0) ones[0] = (f16)1.0f;
  f16x8 w3A[2][2];
#pragma unroll
  for (int mt = 0; mt < 2; ++mt)
#pragma unroll
    for (int q = 0; q < 2; ++q) {
      f16x8 v = {};
      if (arow < 3) {
#pragma unroll
        for (int j = 0; j < 8; ++j)
          v[j] = (f16)w3[arow*256 + mhalf + mt*32 + q*16 + half*8 + j];
      }
      w3A[mt][q] = v;
    }
  const float b3r0 = b3[0], b3r1 = b3[1], b3r2 = b3[2];
  const size_t outL = (size_t)Bsz * 2;
  const u32 rk = ((u32)(arow & 15)) << 4;

  // phase B: h1(tile) via MFMA -> repack -> swizzled f16 writes into h1[buf]
  auto PHASE_B = [&](int buf) {
    unsigned char* h1b = lds + H1_OFF + (u32)buf*65536;
    const float* xb_src = xsf + (u32)buf*384;
#pragma unroll
    for (int nt = 0; nt < 2; ++nt) {
      const int r = rowblk + nt*32 + arow;
      f16x8 xb = {};
      if (half == 0) {
        const float* xr = xb_src + r*3;
        xb[0] = (f16)xr[0]; xb[1] = (f16)xr[1]; xb[2] = (f16)xr[2];
        xb[3] = (f16)1.0f;
      }
#pragma unroll
      for (int mt = 0; mt < 2; ++mt) {
        f32x16 h = {};
        h = __builtin_amdgcn_mfma_f32_32x32x16_f16(w1A[mt], xb, h, 0,0,0);
#pragma unroll
        for (int q = 0; q < 2; ++q) {
          const int i0 = q*8;
          const float c0 = fmaxf(h[i0+0], 0.f), c1 = fmaxf(h[i0+1], 0.f);
          const float c2 = fmaxf(h[i0+2], 0.f), c3 = fmaxf(h[i0+3], 0.f);
          const float c4 = fmaxf(h[i0+4], 0.f), c5 = fmaxf(h[i0+5], 0.f);
          const float c6 = fmaxf(h[i0+6], 0.f), c7 = fmaxf(h[i0+7], 0.f);
          u32 P = __builtin_bit_cast(u32, __builtin_amdgcn_cvt_pkrtz(c0, c1));
          u32 Q = __builtin_bit_cast(u32, __builtin_amdgcn_cvt_pkrtz(c2, c3));
          u32 R = __builtin_bit_cast(u32, __builtin_amdgcn_cvt_pkrtz(c4, c5));
          u32 S = __builtin_bit_cast(u32, __builtin_amdgcn_cvt_pkrtz(c6, c7));
          asm("v_permlane32_swap_b32 %0, %1" : "+v"(P), "+v"(R));
          asm("v_permlane32_swap_b32 %0, %1" : "+v"(Q), "+v"(S));
          u32x4 w; w[0]=P; w[1]=Q; w[2]=R; w[3]=S;
          const u32 slot = (u32)((mhalf + mt*32 + q*16)*2 + half*16);
          *(u32x4*)(h1b + ((u32)r << 9) + (slot ^ rk)) = w;
        }
      }
    }
  };

  __syncthreads();
  PHASE_B(0);
  __syncthreads();

  for (int tl = 0; tl < tpb; ++tl) {
    const int cur = tl & 1, nxt = cur ^ 1;

    // ---- phase C: h2^T = w2·h1^T (+bias via MFMA init) ----
    f32x16 acc[2][2];
#pragma unroll
    for (int mt = 0; mt < 2; ++mt)
#pragma unroll
      for (int nt = 0; nt < 2; ++nt) {
        f32x16 z = {};
        acc[mt][nt] = __builtin_amdgcn_mfma_f32_32x32x16_f16(b2A[mt], ones, z, 0,0,0);
      }
    {
      const unsigned char* h1b = lds + H1_OFF + (u32)cur*65536;
      const u32 cb = (u32)half << 4;
#pragma unroll
      for (int ks = 0; ks < 16; ++ks) {
        f16x8 fr[2];
#pragma unroll
        for (int nt = 0; nt < 2; ++nt)
          fr[nt] = *(const f16x8*)(h1b + ((u32)(rowblk + nt*32 + arow) << 9)
                                   + (((((u32)ks) << 5) + cb) ^ rk));
#pragma unroll
        for (int mt = 0; mt < 2; ++mt)
#pragma unroll
          for (int nt = 0; nt < 2; ++nt)
            acc[mt][nt] = __builtin_amdgcn_mfma_f32_32x32x16_f16(w2A[mt][ks], fr[nt], acc[mt][nt], 0,0,0);
      }
    }

    // ---- phase E: relu + repack + w3-MFMA -> partials ----
#pragma unroll
    for (int nt = 0; nt < 2; ++nt) {
      f32x16 a3 = {};
#pragma unroll
      for (int mt = 0; mt < 2; ++mt)
#pragma unroll
        for (int q = 0; q < 2; ++q) {
          const int i0 = q*8;
          const float c0 = fmaxf(acc[mt][nt][i0+0], 0.f), c1 = fmaxf(acc[mt][nt][i0+1], 0.f);
          const float c2 = fmaxf(acc[mt][nt][i0+2], 0.f), c3 = fmaxf(acc[mt][nt][i0+3], 0.f);
          const float c4 = fmaxf(acc[mt][nt][i0+4], 0.f), c5 = fmaxf(acc[mt][nt][i0+5], 0.f);
          const float c6 = fmaxf(acc[mt][nt][i0+6], 0.f), c7 = fmaxf(acc[mt][nt][i0+7], 0.f);
          u32 P = __builtin_bit_cast(u32, __builtin_amdgcn_cvt_pkrtz(c0, c1));
          u32 Q = __builtin_bit_cast(u32, __builtin_amdgcn_cvt_pkrtz(c2, c3));
          u32 R = __builtin_bit_cast(u32, __builtin_amdgcn_cvt_pkrtz(c4, c5));
          u32 S = __builtin_bit_cast(u32, __builtin_amdgcn_cvt_pkrtz(c6, c7));
          asm("v_permlane32_swap_b32 %0, %1" : "+v"(P), "+v"(R));
          asm("v_permlane32_swap_b32 %0, %1" : "+v"(Q), "+v"(S));
          u32x4 w; w[0]=P; w[1]=Q; w[2]=R; w[3]=S;
          a3 = __builtin_amdgcn_mfma_f32_32x32x16_f16(w3A[mt][q], __builtin_bit_cast(f16x8, w), a3, 0,0,0);
        }
      if (half == 0) {
        float* pr = partf + (u32)cur*1536 + (u32)(cw*128 + rowblk + nt*32 + arow)*3;
        pr[0] = a3[0]; pr[1] = a3[1]; pr[2] = a3[2];
      }
    }

    // ---- phase B(t+1) into h1[nxt] ----
    if (tl + 1 < tpb) PHASE_B(nxt);

    // ---- stage x(t+2) into xs[cur] (waves 6-7 tail threads) ----
    if (tl + 2 < tpb && tid >= 416) {
      const int i = tid - 416;   // 0..95
      ((float4*)(xsf + (u32)cur*384))[i] =
          ((const float4*)x)[(size_t)(t0 + tl + 2)*96 + i];
    }

    // ---- final(t-1): sum partials, parity epilogue, store ----
    if (tl > 0 && tid < MTILE) {
      const int r = tid;
      const float* pb = partf + (u32)nxt*1536;
      float l0 = b3r0, l1 = b3r1, l2 = b3r2;
#pragma unroll
      for (int c4 = 0; c4 < 4; ++c4) {
        const float* pr = pb + (u32)(c4*128 + r)*3;
        l0 += pr[0]; l1 += pr[1]; l2 += pr[2];
      }
      const float inv1p2e = 1.0f / (1.0f + 2.0f * 1e-5f);
      const float tt0 = (1.0f - 2.0f / (1.0f + __expf(-l0))) * inv1p2e;
      const float tt1 = (1.0f - 2.0f / (1.0f + __expf(-l1))) * inv1p2e;
      const float tt2 = (1.0f - 2.0f / (1.0f + __expf(-l2))) * inv1p2e;
      const float pred1 = 0.5f * (1.0f - tt0 * tt1 * tt2);
      const size_t grow = (size_t)(t0 + tl - 1)*MTILE + r;
      float2 ov;
      ov.x = (1.0f - pred1 + 0.001f) * (1.0f / 1.002f);
      ov.y = (pred1 + 0.001f) * (1.0f / 1.002f);
      *(float2*)(out + grow*2) = ov;
      out[outL + grow*3 + 0] = l0;
      out[outL + grow*3 + 1] = l1;
      out[outL + grow*3 + 2] = l2;
    }
    __syncthreads();
  }

  // drain: final(tpb-1)
  if (tid < MTILE) {
    const int r = tid;
    const float* pb = partf + (u32)((tpb - 1) & 1)*1536;
    float l0 = b3r0, l1 = b3r1, l2 = b3r2;
#pragma unroll
    for (int c4 = 0; c4 < 4; ++c4) {
      const float* pr = pb + (u32)(c4*128 + r)*3;
      l0 += pr[0]; l1 += pr[1]; l2 += pr[2];
    }
    const float inv1p2e = 1.0f / (1.0f + 2.0f * 1e-5f);
    const float tt0 = (1.0f - 2.0f / (1.0f + __expf(-l0))) * inv1p2e;
    const float tt1 = (1.0f - 2.0f / (1.0f + __expf(-l1))) * inv1p2e;
    const float tt2 = (1.0f - 2.0f / (1.0f + __expf(-l2))) * inv1p2e;
    const float pred1 = 0.5f * (1.0f - tt0 * tt1 * tt2);
    const size_t grow = (size_t)(t0 + tpb - 1)*MTILE + r;
    float2 ov;
    ov.x = (1.0f - pred1 + 0.001f) * (1.0f / 1.002f);
    ov.y = (pred1 + 0.001f) * (1.0f / 1.002f);
    *(float2*)(out + grow*2) = ov;
    out[outL + grow*3 + 0] = l0;
    out[outL + grow*3 + 1] = l1;
    out[outL + grow*3 + 2] = l2;
  }
}

extern "C" void kernel_launch(void* const* d_in, const int* in_sizes, int n_in,
                              void* d_out, int out_size, void* d_ws, size_t ws_size,
                              hipStream_t stream) {
  const float* x  = (const float*)d_in[0];
  const float* w1 = (const float*)d_in[1];
  const float* b1 = (const float*)d_in[2];
  const float* w2 = (const float*)d_in[3];
  const float* b2 = (const float*)d_in[4];
  const float* w3 = (const float*)d_in[5];
  const float* b3 = (const float*)d_in[6];
  float* out = (float*)d_out;
  const int Bsz = in_sizes[0] / 3;

  dim3 grid(NBLK), block(THREADS);
  fused_mlp_parity<<<grid, block, 0, stream>>>(x, w1, b1, w2, b2, w3, b3, out, Bsz);
}

// Round 6
// 218.117 us; speedup vs baseline: 1.2108x; 1.2108x over previous
//
#include <hip/hip_runtime.h>

typedef _Float16 f16;
typedef _Float16 f16x8 __attribute__((ext_vector_type(8)));
typedef float f32x16 __attribute__((ext_vector_type(16)));
typedef unsigned int u32;
typedef unsigned int u32x4 __attribute__((ext_vector_type(4)));

#define THREADS 512
#define MTILE   128
#define NBLK    256

// LDS layout (bytes)
#define H1_OFF   0        // 2 bufs × f16[128 rows][512 B], 16B XOR key (r&15)<<4
#define XS_OFF   131072   // 2 bufs × f32[128*3] = 2×1536
#define PART_OFF 134144   // 2 bufs × f32[8 wave][128 row][3] = 2×12288
#define LDS_BYTES 158720

// relu 8 lanes-worth of f32 acc -> packed f16 fragment (verified rounds 3-5)
template <int I0>
static __device__ __forceinline__ u32x4 relu_pack8(const f32x16& h) {
  const float c0 = fmaxf(h[I0+0], 0.f), c1 = fmaxf(h[I0+1], 0.f);
  const float c2 = fmaxf(h[I0+2], 0.f), c3 = fmaxf(h[I0+3], 0.f);
  const float c4 = fmaxf(h[I0+4], 0.f), c5 = fmaxf(h[I0+5], 0.f);
  const float c6 = fmaxf(h[I0+6], 0.f), c7 = fmaxf(h[I0+7], 0.f);
  u32 P = __builtin_bit_cast(u32, __builtin_amdgcn_cvt_pkrtz(c0, c1));
  u32 Q = __builtin_bit_cast(u32, __builtin_amdgcn_cvt_pkrtz(c2, c3));
  u32 R = __builtin_bit_cast(u32, __builtin_amdgcn_cvt_pkrtz(c4, c5));
  u32 S = __builtin_bit_cast(u32, __builtin_amdgcn_cvt_pkrtz(c6, c7));
  asm("v_permlane32_swap_b32 %0, %1" : "+v"(P), "+v"(R));
  asm("v_permlane32_swap_b32 %0, %1" : "+v"(Q), "+v"(S));
  u32x4 w; w[0] = P; w[1] = Q; w[2] = R; w[3] = S;
  return w;
}

__global__ __launch_bounds__(THREADS, 1)
void fused_mlp_parity(const float* __restrict__ x,
                      const float* __restrict__ w1,
                      const float* __restrict__ b1,
                      const float* __restrict__ w2,
                      const float* __restrict__ b2,
                      const float* __restrict__ w3,
                      const float* __restrict__ b3,
                      float* __restrict__ out, int Bsz) {
  __shared__ __align__(128) unsigned char lds[LDS_BYTES];
  const int tid  = threadIdx.x;
  const int lane = tid & 63;
  const int wave = tid >> 6;          // 8 waves, each owns 32 h-cols
  const int arow = lane & 31;
  const int half = lane >> 5;

  const int ntiles = Bsz / MTILE;
  const int tpb    = ntiles / NBLK;   // 32 at B=1M
  const int t0     = blockIdx.x * tpb;

  float* xsf   = (float*)(lds + XS_OFF);    // + buf*384 floats
  float* partf = (float*)(lds + PART_OFF);  // + buf*3072 floats

  // ---- prologue: stage xs[0], xs[1] ----
  {
    const float4* xg = (const float4*)x;
    float4* xv = (float4*)xsf;
    if (tid < 96)                      xv[tid]        = xg[(size_t)t0*96 + tid];
    else if (tid >= 128 && tid < 224)  xv[96 + tid-128] = xg[(size_t)(t0+1)*96 + (tid-128)];
  }

  // ---- register-resident operands (round-4 proven shape: 32 cols/wave) ----
  const int col = (wave << 5) + arow;
  f16x8 w2A[16];
#pragma unroll
  for (int ks = 0; ks < 16; ++ks) {
    const float* src = w2 + (size_t)col*256 + ks*16 + half*8;
    float4 u0 = *(const float4*)src;
    float4 u1 = *(const float4*)(src + 4);
    f16x8 v;
    v[0]=(f16)u0.x; v[1]=(f16)u0.y; v[2]=(f16)u0.z; v[3]=(f16)u0.w;
    v[4]=(f16)u1.x; v[5]=(f16)u1.y; v[6]=(f16)u1.z; v[7]=(f16)u1.w;
    w2A[ks] = v;
  }
  f16x8 w1A = {};
  if (half == 0) {
    w1A[0] = (f16)w1[col*3+0]; w1A[1] = (f16)w1[col*3+1];
    w1A[2] = (f16)w1[col*3+2]; w1A[3] = (f16)b1[col];
  }
  f16x8 b2A = {};  if (half == 0) b2A[0] = (f16)b2[col];
  f16x8 ones = {}; if (half == 0) ones[0] = (f16)1.0f;
  f16x8 w3A[2];
#pragma unroll
  for (int q = 0; q < 2; ++q) {
    f16x8 v = {};
    if (arow < 3) {
#pragma unroll
      for (int j = 0; j < 8; ++j)
        v[j] = (f16)w3[arow*256 + (wave<<5) + q*16 + half*8 + j];
    }
    w3A[q] = v;
  }
  const float b3r0 = b3[0], b3r1 = b3[1], b3r2 = b3[2];
  const size_t outL = (size_t)Bsz * 2;
  const u32 rk = ((u32)(arow & 15)) << 4;

  // phase B: h1(tile in buf) via MFMA -> repack -> swizzled b128 writes
  auto PHASE_B = [&](int buf) {
    unsigned char* h1b = lds + H1_OFF + (u32)buf*65536;
    const float* xb_src = xsf + (u32)buf*384;
#pragma unroll
    for (int nt = 0; nt < 4; ++nt) {
      const int r = nt*32 + arow;
      f16x8 xb = {};
      if (half == 0) {
        const float* xr = xb_src + r*3;
        xb[0] = (f16)xr[0]; xb[1] = (f16)xr[1]; xb[2] = (f16)xr[2];
        xb[3] = (f16)1.0f;
      }
      f32x16 h = {};
      h = __builtin_amdgcn_mfma_f32_32x32x16_f16(w1A, xb, h, 0,0,0);
      const u32 rowbase = ((u32)r << 9);
      {
        u32x4 w = relu_pack8<0>(h);
        const u32 slot = (u32)(((wave<<5) + 0*16)*2 + half*16);
        *(u32x4*)(h1b + rowbase + (slot ^ rk)) = w;
      }
      {
        u32x4 w = relu_pack8<8>(h);
        const u32 slot = (u32)(((wave<<5) + 1*16)*2 + half*16);
        *(u32x4*)(h1b + rowbase + (slot ^ rk)) = w;
      }
    }
  };

  __syncthreads();
  PHASE_B(0);
  __syncthreads();

  for (int tl = 0; tl < tpb; ++tl) {
    const int cur = tl & 1, nxt = cur ^ 1;
    const unsigned char* h1b = lds + H1_OFF + (u32)cur*65536;
    const u32 cb = (u32)half << 4;

    // ---- fused C+E per nt-pair: 2 independent MFMA chains, low live-regs ----
#pragma unroll
    for (int ntp = 0; ntp < 2; ++ntp) {
      f32x16 acc0, acc1;
      {
        f32x16 z = {};
        acc0 = __builtin_amdgcn_mfma_f32_32x32x16_f16(b2A, ones, z, 0,0,0);
        acc1 = __builtin_amdgcn_mfma_f32_32x32x16_f16(b2A, ones, z, 0,0,0);
      }
      const u32 row0 = (u32)((ntp*2 + 0)*32 + arow) << 9;
      const u32 row1 = (u32)((ntp*2 + 1)*32 + arow) << 9;
#pragma unroll
      for (int ks = 0; ks < 16; ++ks) {
        const u32 coff = ((((u32)ks) << 5) + cb) ^ rk;
        f16x8 fr0 = *(const f16x8*)(h1b + row0 + coff);
        f16x8 fr1 = *(const f16x8*)(h1b + row1 + coff);
        acc0 = __builtin_amdgcn_mfma_f32_32x32x16_f16(w2A[ks], fr0, acc0, 0,0,0);
        acc1 = __builtin_amdgcn_mfma_f32_32x32x16_f16(w2A[ks], fr1, acc1, 0,0,0);
      }
      // phase E for both nt of the pair
#pragma unroll
      for (int p = 0; p < 2; ++p) {
        const f32x16& a = p ? acc1 : acc0;
        const int nt = ntp*2 + p;
        f32x16 a3 = {};
        {
          u32x4 w = relu_pack8<0>(a);
          a3 = __builtin_amdgcn_mfma_f32_32x32x16_f16(w3A[0], __builtin_bit_cast(f16x8, w), a3, 0,0,0);
        }
        {
          u32x4 w = relu_pack8<8>(a);
          a3 = __builtin_amdgcn_mfma_f32_32x32x16_f16(w3A[1], __builtin_bit_cast(f16x8, w), a3, 0,0,0);
        }
        if (half == 0) {
          float* pr = partf + (u32)cur*3072 + (u32)((wave<<7) + nt*32 + arow)*3;
          pr[0] = a3[0]; pr[1] = a3[1]; pr[2] = a3[2];
        }
      }
    }

    // ---- phase B(t+1) into h1[nxt] ----
    if (tl + 1 < tpb) PHASE_B(nxt);

    // ---- stage x(t+2) into xs[cur] (tail threads of waves 6-7) ----
    if (tl + 2 < tpb && tid >= 416) {
      const int i = tid - 416;   // 0..95
      ((float4*)(xsf + (u32)cur*384))[i] =
          ((const float4*)x)[(size_t)(t0 + tl + 2)*96 + i];
    }

    // ---- final(t-1): sum 8 wave-partials, parity epilogue, store ----
    if (tl > 0 && tid < MTILE) {
      const int r = tid;
      const float* pb = partf + (u32)nxt*3072;
      float l0 = b3r0, l1 = b3r1, l2 = b3r2;
#pragma unroll
      for (int w8 = 0; w8 < 8; ++w8) {
        const float* pr = pb + (u32)((w8<<7) + r)*3;
        l0 += pr[0]; l1 += pr[1]; l2 += pr[2];
      }
      const float inv1p2e = 1.0f / (1.0f + 2.0f * 1e-5f);
      const float tt0 = (1.0f - 2.0f / (1.0f + __expf(-l0))) * inv1p2e;
      const float tt1 = (1.0f - 2.0f / (1.0f + __expf(-l1))) * inv1p2e;
      const float tt2 = (1.0f - 2.0f / (1.0f + __expf(-l2))) * inv1p2e;
      const float pred1 = 0.5f * (1.0f - tt0 * tt1 * tt2);
      const size_t grow = (size_t)(t0 + tl - 1)*MTILE + r;
      float2 ov;
      ov.x = (1.0f - pred1 + 0.001f) * (1.0f / 1.002f);
      ov.y = (pred1 + 0.001f) * (1.0f / 1.002f);
      *(float2*)(out + grow*2) = ov;
      out[outL + grow*3 + 0] = l0;
      out[outL + grow*3 + 1] = l1;
      out[outL + grow*3 + 2] = l2;
    }
    __syncthreads();
  }

  // ---- drain: final(tpb-1) ----
  if (tid < MTILE) {
    const int r = tid;
    const float* pb = partf + (u32)((tpb - 1) & 1)*3072;
    float l0 = b3r0, l1 = b3r1, l2 = b3r2;
#pragma unroll
    for (int w8 = 0; w8 < 8; ++w8) {
      const float* pr = pb + (u32)((w8<<7) + r)*3;
      l0 += pr[0]; l1 += pr[1]; l2 += pr[2];
    }
    const float inv1p2e = 1.0f / (1.0f + 2.0f * 1e-5f);
    const float tt0 = (1.0f - 2.0f / (1.0f + __expf(-l0))) * inv1p2e;
    const float tt1 = (1.0f - 2.0f / (1.0f + __expf(-l1))) * inv1p2e;
    const float tt2 = (1.0f - 2.0f / (1.0f + __expf(-l2))) * inv1p2e;
    const float pred1 = 0.5f * (1.0f - tt0 * tt1 * tt2);
    const size_t grow = (size_t)(t0 + tpb - 1)*MTILE + r;
    float2 ov;
    ov.x = (1.0f - pred1 + 0.001f) * (1.0f / 1.002f);
    ov.y = (pred1 + 0.001f) * (1.0f / 1.002f);
    *(float2*)(out + grow*2) = ov;
    out[outL + grow*3 + 0] = l0;
    out[outL + grow*3 + 1] = l1;
    out[outL + grow*3 + 2] = l2;
  }
}

extern "C" void kernel_launch(void* const* d_in, const int* in_sizes, int n_in,
                              void* d_out, int out_size, void* d_ws, size_t ws_size,
                              hipStream_t stream) {
  const float* x  = (const float*)d_in[0];
  const float* w1 = (const float*)d_in[1];
  const float* b1 = (const float*)d_in[2];
  const float* w2 = (const float*)d_in[3];
  const float* b2 = (const float*)d_in[4];
  const float* w3 = (const float*)d_in[5];
  const float* b3 = (const float*)d_in[6];
  float* out = (float*)d_out;
  const int Bsz = in_sizes[0] / 3;

  dim3 grid(NBLK), block(THREADS);
  fused_mlp_parity<<<grid, block, 0, stream>>>(x, w1, b1, w2, b2, w3, b3, out, Bsz);
}